// Round 13
// baseline (300.672 us; speedup 1.0000x reference)
//
#include <hip/hip_runtime.h>
#include <cstdint>

using f32x4 = __attribute__((ext_vector_type(4))) float;
using s16x8 = __attribute__((ext_vector_type(8))) short;

__device__ __forceinline__ short f2bf(float f) {
    union { float f; uint32_t u; } x{f};
    uint32_t r = (x.u + 0x7fffu + ((x.u >> 16) & 1u)) >> 16;
    return (short)r;
}
__device__ __forceinline__ float bf2f(short s) {
    union { uint32_t u; float f; } x;
    x.u = ((uint32_t)(uint16_t)s) << 16;
    return x.f;
}

#define MFMA16(a, b, c) __builtin_amdgcn_mfma_f32_16x16x32_bf16(a, b, c, 0, 0, 0)

// barrier that does NOT drain vmcnt: global stores/loads stay in flight.
__device__ __forceinline__ void bar_lgkm() {
    asm volatile("s_waitcnt lgkmcnt(0)\n\ts_barrier" ::: "memory");
}

__device__ __forceinline__ void gl_lds16(const void* g, void* l) {
    __builtin_amdgcn_global_load_lds(
        (const __attribute__((address_space(1))) void*)(const void*)g,
        (__attribute__((address_space(3))) void*)l, 16, 0, 0);
}

// ---------------------------------------------------------------------------
// prep: blocks 0-191 = coalesced 64x64 LDS-transpose (Wq, Wkv);
//       blocks 192-399 = scalar W2T (row-permute, stride-2 reads) + WpT
// ---------------------------------------------------------------------------
__global__ __launch_bounds__(256) void prep_all(
    const float* __restrict__ Wq, const float* __restrict__ Wsr,
    const float* __restrict__ Wkv, const float* __restrict__ Wp,
    short* __restrict__ WqT, short* __restrict__ W2T,
    short* __restrict__ WkvT, short* __restrict__ WpT)
{
    const int b = blockIdx.x, tid = threadIdx.x;
    if (b < 192) {
        const float* src; short* dst; int K, N, tk, tn;
        if (b < 64) { src = Wq;  dst = WqT;  K = 512; N = 512;  tk = b >> 3; tn = b & 7; }
        else { int u = b - 64; src = Wkv; dst = WkvT; K = 512; N = 1024; tk = u >> 4; tn = u & 15; }
        const int k0 = tk * 64, n0 = tn * 64;
        __shared__ float t[64][65];
        const int lr = tid >> 2, lc = (tid & 3) * 16;
        const float* s = src + (size_t)(k0 + lr) * N + n0 + lc;
        float4 a0 = *(const float4*)s, a1 = *(const float4*)(s + 4);
        float4 a2 = *(const float4*)(s + 8), a3 = *(const float4*)(s + 12);
        *(float4*)&t[lr][lc]      = a0; *(float4*)&t[lr][lc + 4]  = a1;
        *(float4*)&t[lr][lc + 8]  = a2; *(float4*)&t[lr][lc + 12] = a3;
        __syncthreads();
        const int wn = tid >> 2, wk = (tid & 3) * 16;
        s16x8 o0, o1;
#pragma unroll
        for (int j = 0; j < 8; ++j) {
            o0[j] = f2bf(t[wk + j][wn]);
            o1[j] = f2bf(t[wk + 8 + j][wn]);
        }
        short* d = dst + (size_t)(n0 + wn) * K + k0 + wk;
        *(s16x8*)d = o0;
        *(s16x8*)(d + 8) = o1;
    } else {
        for (int u = (b - 192) * 256 + tid; u < 524288 + 4096; u += 208 * 256) {
            if (u < 524288) {
                int o = u >> 10, kk = u & 1023;
                int s2 = kk >> 9, i = kk & 511;
                W2T[u] = f2bf(Wsr[o * 1024 + i * 2 + s2]);     // W2T[o][s*512+i]
            } else {
                int v = u - 524288;
                int e = v >> 6, dh = v & 63;
                WpT[v] = f2bf(Wp[dh * 64 + e]);                // WpT[e][dh]
            }
        }
    }
}

// ---------------------------------------------------------------------------
// Fused Q-gemm (u 0-511) + conv-gemm (u 512-767), both AF32 staged.
// XCD-affinity swizzle. Q epilogue folds 0.125*log2(e) for exp2 softmax.
// Conv epilogue also accumulates per-row LN stats (sum, sumsq) via 16-lane
// shfl reduce + device atomics into ssum/ssq (zeroed by hipMemsetAsync).
// ---------------------------------------------------------------------------
__global__ __launch_bounds__(256) void gemm_qconv(
    const float* __restrict__ x, const float* __restrict__ xkv,
    const short* __restrict__ WqT, const short* __restrict__ W2T,
    const float* __restrict__ bq, const float* __restrict__ bsr,
    short* __restrict__ Qb, float* __restrict__ xkf,
    float* __restrict__ ssum, float* __restrict__ ssq)
{
    __shared__ short As[128 * 32];
    __shared__ short Bs[128 * 32];
    const int tid = threadIdx.x;
    const int wv = tid >> 6, lane = tid & 63;
    const int l15 = lane & 15, lhi = lane >> 4;
    const int wr = wv >> 1, wc = wv & 1;

    const int bid = blockIdx.x;
    const int u0 = (bid & 7) * 96 + (bid >> 3);          // 768 = 8 XCDs x 96
    const bool isQ = u0 < 512;
    const int u = isQ ? u0 : u0 - 512;
    const int m0 = (u >> 2) * 128, n0 = (u & 3) * 128;
    const int K = isQ ? 512 : 1024;
    const float* A = isQ ? x : xkv;
    const short* BT = isQ ? WqT : W2T;
    const float* bias = isQ ? bq : bsr;

    f32x4 acc[4][4] = {};

    const int nk = K >> 5;
    for (int kk = 0; kk < nk; ++kk) {
#pragma unroll
        for (int i = 0; i < 2; ++i) {
            int fo = wv * 2048 + i * 1024 + lane * 16;   // byte offset in 8KB tile
            int row = fo >> 6;
            int ks  = (fo & 63) >> 1;
            const float* src = A + (size_t)(m0 + row) * K + kk * 32 + ks;
            float4 a0 = *(const float4*)src;
            float4 a1 = *(const float4*)(src + 4);
            s16x8 pk;
            pk[0] = f2bf(a0.x); pk[1] = f2bf(a0.y); pk[2] = f2bf(a0.z); pk[3] = f2bf(a0.w);
            pk[4] = f2bf(a1.x); pk[5] = f2bf(a1.y); pk[6] = f2bf(a1.z); pk[7] = f2bf(a1.w);
            *(s16x8*)((char*)As + fo) = pk;
            gl_lds16(BT + (size_t)(n0 + row) * K + kk * 32 + ks, (char*)Bs + fo);
        }
        __syncthreads();
        s16x8 a[4], b[4];
#pragma unroll
        for (int mi = 0; mi < 4; ++mi)
            a[mi] = *(const s16x8*)&As[(wr * 64 + mi * 16 + l15) * 32 + lhi * 8];
#pragma unroll
        for (int ni = 0; ni < 4; ++ni)
            b[ni] = *(const s16x8*)&Bs[(wc * 64 + ni * 16 + l15) * 32 + lhi * 8];
#pragma unroll
        for (int mi = 0; mi < 4; ++mi)
#pragma unroll
            for (int ni = 0; ni < 4; ++ni)
                acc[mi][ni] = MFMA16(a[mi], b[ni], acc[mi][ni]);
        __syncthreads();
    }

    if (isQ) {
#pragma unroll
        for (int mi = 0; mi < 4; ++mi)
#pragma unroll
            for (int ni = 0; ni < 4; ++ni)
#pragma unroll
                for (int r = 0; r < 4; ++r) {
                    int grow = m0 + wr * 64 + mi * 16 + lhi * 4 + r;
                    int gcol = n0 + wc * 64 + ni * 16 + l15;
                    float v = acc[mi][ni][r] + bias[gcol];
                    // Qb[g=h*8+b][n][dh], scale 0.125*log2(e) for exp2 softmax
                    int h = gcol >> 6, dh = gcol & 63;
                    int bb = grow >> 11, n = grow & 2047;
                    Qb[(((size_t)(h * 8 + bb) * 2048 + n) << 6) + dh] = f2bf(v * 0.18033688f);
                }
    } else {
#pragma unroll
        for (int mi = 0; mi < 4; ++mi) {
#pragma unroll
            for (int r = 0; r < 4; ++r) {
                int grow = m0 + wr * 64 + mi * 16 + lhi * 4 + r;
                float s = 0.f, q = 0.f;
#pragma unroll
                for (int ni = 0; ni < 4; ++ni) {
                    int gcol = n0 + wc * 64 + ni * 16 + l15;
                    float v = acc[mi][ni][r] + bias[gcol];
                    xkf[(size_t)grow * 512 + gcol] = v;
                    s += v; q += v * v;
                }
                s += __shfl_xor(s, 1); q += __shfl_xor(q, 1);
                s += __shfl_xor(s, 2); q += __shfl_xor(q, 2);
                s += __shfl_xor(s, 4); q += __shfl_xor(q, 4);
                s += __shfl_xor(s, 8); q += __shfl_xor(q, 8);
                if (l15 == 0) {
                    atomicAdd(&ssum[grow], s);
                    atomicAdd(&ssq[grow], q);
                }
            }
        }
    }
}

// ---------------------------------------------------------------------------
// KV gemm with fused LayerNorm: A-staging reads conv output xkf (f32),
// applies (v-mean)*rstd*gamma+beta inline (stats from ssum/ssq), converts to
// bf16, ds_write_b128.  KV scatter epilogue (permute-bug layout).
// XCD-affinity: XCD x owns u in [x*64, x*64+64).
// ---------------------------------------------------------------------------
__global__ __launch_bounds__(256) void gemm_kv(
    const float* __restrict__ xkf, const short* __restrict__ BT,
    const float* __restrict__ ssum, const float* __restrict__ ssq,
    const float* __restrict__ gamma, const float* __restrict__ beta,
    const float* __restrict__ bias,
    short* __restrict__ Kb, short* __restrict__ VTb)
{
    __shared__ short As[128 * 32];
    __shared__ short Bs[128 * 32];
    const int tid = threadIdx.x;
    const int wv = tid >> 6, lane = tid & 63;
    const int l15 = lane & 15, lhi = lane >> 4;
    const int wr = wv >> 1, wc = wv & 1;
    const int K = 512;
    const int u = (blockIdx.x & 7) * 64 + (blockIdx.x >> 3);   // 512 = 8 x 64
    const int m0 = (u >> 3) * 128, n0 = (u & 7) * 128;

    f32x4 acc[4][4] = {};

    const int nk = K >> 5;
    for (int kk = 0; kk < nk; ++kk) {
#pragma unroll
        for (int i = 0; i < 2; ++i) {
            int fo = wv * 2048 + i * 1024 + lane * 16;
            int row = fo >> 6;
            int ks  = (fo & 63) >> 1;
            const int arow = m0 + row;
            const float* src = xkf + (size_t)arow * 512 + kk * 32 + ks;
            float4 a0 = *(const float4*)src;
            float4 a1 = *(const float4*)(src + 4);
            float mean = ssum[arow] * (1.f / 512.f);
            float var  = ssq[arow] * (1.f / 512.f) - mean * mean;
            float rstd = rsqrtf(var + 1e-5f);
            const float* gp = gamma + kk * 32 + ks;
            const float* bp = beta  + kk * 32 + ks;
            float4 g0 = *(const float4*)gp, g1 = *(const float4*)(gp + 4);
            float4 e0 = *(const float4*)bp, e1 = *(const float4*)(bp + 4);
            s16x8 pk;
            pk[0] = f2bf((a0.x - mean) * rstd * g0.x + e0.x);
            pk[1] = f2bf((a0.y - mean) * rstd * g0.y + e0.y);
            pk[2] = f2bf((a0.z - mean) * rstd * g0.z + e0.z);
            pk[3] = f2bf((a0.w - mean) * rstd * g0.w + e0.w);
            pk[4] = f2bf((a1.x - mean) * rstd * g1.x + e1.x);
            pk[5] = f2bf((a1.y - mean) * rstd * g1.y + e1.y);
            pk[6] = f2bf((a1.z - mean) * rstd * g1.z + e1.z);
            pk[7] = f2bf((a1.w - mean) * rstd * g1.w + e1.w);
            *(s16x8*)((char*)As + fo) = pk;
            gl_lds16(BT + (size_t)(n0 + row) * K + kk * 32 + ks, (char*)Bs + fo);
        }
        __syncthreads();
        s16x8 a[4], b[4];
#pragma unroll
        for (int mi = 0; mi < 4; ++mi)
            a[mi] = *(const s16x8*)&As[(wr * 64 + mi * 16 + l15) * 32 + lhi * 8];
#pragma unroll
        for (int ni = 0; ni < 4; ++ni)
            b[ni] = *(const s16x8*)&Bs[(wc * 64 + ni * 16 + l15) * 32 + lhi * 8];
#pragma unroll
        for (int mi = 0; mi < 4; ++mi)
#pragma unroll
            for (int ni = 0; ni < 4; ++ni)
                acc[mi][ni] = MFMA16(a[mi], b[ni], acc[mi][ni]);
        __syncthreads();
    }

#pragma unroll
    for (int mi = 0; mi < 4; ++mi) {
#pragma unroll
        for (int ni = 0; ni < 4; ++ni) {
#pragma unroll
            for (int r = 0; r < 4; ++r) {
                int grow = m0 + wr * 64 + mi * 16 + lhi * 4 + r;
                int gcol = n0 + wc * 64 + ni * 16 + l15;
                float v = acc[mi][ni][r] + bias[gcol];
                int kvsel = gcol >> 9, h = (gcol >> 6) & 7, dh = gcol & 63;
                int bb = grow >> 10, t = grow & 1023;
                int g2 = t >> 4, m = ((t & 15) << 6) + bb * 8 + h;
                if (kvsel == 0)
                    Kb[(((size_t)g2 * 1024 + m) << 6) + dh] = f2bf(v);        // K[g][m][d]
                else
                    VTb[(((size_t)g2 * 64 + dh) << 10) + m] = f2bf(v);        // VT[g][dh][m]
            }
        }
    }
}

// ---------------------------------------------------------------------------
// attention: 8 waves (512 thr), 32 q-rows/block, m=1024 split 8 ways.
// lgkm-only barriers; NT attn stores issued FIRST after the phase-1 barrier
// (write stream starts earliest; V prefetched pre-barrier so PV unaffected).
// exp2f softmax (log2e folded into Q). NT ctx stores (write-once).
// __launch_bounds__(512,4): compiler picks ~64 VGPR, NO spills (r11 lesson:
// (512,8) forced 32 VGPR -> 0.9 GB scratch spill traffic, 420 us).
// ---------------------------------------------------------------------------
__global__ __launch_bounds__(512, 4) void attn_kernel(
    const short* __restrict__ Qb, const short* __restrict__ Kb,
    const short* __restrict__ VTb, const short* __restrict__ WpT,
    const float* __restrict__ bp,
    float* __restrict__ ctx_out, float* __restrict__ attn_out)
{
    __shared__ __align__(16) char smem[65536];   // Pl: 32x1024 bf16 | cx: [4][32][68] f32 (aliased)
    __shared__ float sums[8][32];

    // XCD-aware swizzle (4096 blocks, 8 XCDs)
    const int bid = blockIdx.x;
    const int swz = ((bid & 7) << 9) | (bid >> 3);
    const int g  = swz >> 6;
    const int n0 = (swz & 63) << 5;
    const int tid = threadIdx.x;
    const int wv = tid >> 6, lane = tid & 63;
    const int l15 = lane & 15, lhi = lane >> 4;

    // Q a-frags for both row-groups (scale 0.125*log2e folded at Q-gemm)
    s16x8 qa00, qa01, qa10, qa11;
    {
        size_t qb0 = (((size_t)g * 2048 + n0 + l15) << 6) + lhi * 8;
        size_t qb1 = (((size_t)g * 2048 + n0 + 16 + l15) << 6) + lhi * 8;
        qa00 = *(const s16x8*)&Qb[qb0];
        qa01 = *(const s16x8*)&Qb[qb0 + 32];
        qa10 = *(const s16x8*)&Qb[qb1];
        qa11 = *(const s16x8*)&Qb[qb1 + 32];
    }

    // ---- phase 1: QK^T over this wave's m-chunk (128) x 32 rows, 4-deep K pipe ----
    const short* Kg = Kb + ((size_t)g << 16);
    s16x8 kf[4][2];
#pragma unroll
    for (int p = 0; p < 4; ++p) {
        const short* kr = Kg + (((wv * 8 + p) * 16 + l15) << 6) + lhi * 8;
        kf[p][0] = *(const s16x8*)kr;
        kf[p][1] = *(const s16x8*)(kr + 32);
    }
    float ps0[4] = {}, ps1[4] = {};
#pragma unroll
    for (int i = 0; i < 8; ++i) {
        s16x8 k0 = kf[i & 3][0], k1 = kf[i & 3][1];
        if (i < 4) {   // refill slot with iter i+4 (static index, full unroll)
            const short* kr = Kg + (((wv * 8 + i + 4) * 16 + l15) << 6) + lhi * 8;
            kf[i][0] = *(const s16x8*)kr;
            kf[i][1] = *(const s16x8*)(kr + 32);
        }
        int mf = wv * 8 + i;
        f32x4 s0 = {0.f, 0.f, 0.f, 0.f};
        s0 = MFMA16(qa00, k0, s0);
        s0 = MFMA16(qa01, k1, s0);
        f32x4 s1 = {0.f, 0.f, 0.f, 0.f};
        s1 = MFMA16(qa10, k0, s1);
        s1 = MFMA16(qa11, k1, s1);
#pragma unroll
        for (int r = 0; r < 4; ++r) {
            float e0 = exp2f(s0[r]);
            ps0[r] += e0;
            int row0 = lhi * 4 + r;
            int byte0 = ((row0 << 11) + ((mf * 16 + l15) << 1)) ^ ((row0 & 7) << 4);
            *(short*)(smem + byte0) = f2bf(e0);
            float e1 = exp2f(s1[r]);
            ps1[r] += e1;
            int row1 = 16 + lhi * 4 + r;
            int byte1 = ((row1 << 11) + ((mf * 16 + l15) << 1)) ^ ((row1 & 7) << 4);
            *(short*)(smem + byte1) = f2bf(e1);
        }
    }

    // V prologue: issue before the barrier (vmcnt not drained by bar_lgkm)
    const short* Vg = VTb + ((size_t)g << 16);
    s16x8 vb[2][4];
#pragma unroll
    for (int ni = 0; ni < 4; ++ni) {
        vb[0][ni] = *(const s16x8*)&Vg[((ni * 16 + l15) << 10) + wv * 128 + lhi * 8];
        vb[1][ni] = *(const s16x8*)&Vg[((ni * 16 + l15) << 10) + wv * 128 + 32 + lhi * 8];
    }

#pragma unroll
    for (int r = 0; r < 4; ++r) {
        float v0 = ps0[r], v1 = ps1[r];
        v0 += __shfl_xor(v0, 1); v1 += __shfl_xor(v1, 1);
        v0 += __shfl_xor(v0, 2); v1 += __shfl_xor(v1, 2);
        v0 += __shfl_xor(v0, 4); v1 += __shfl_xor(v1, 4);
        v0 += __shfl_xor(v0, 8); v1 += __shfl_xor(v1, 8);
        ps0[r] = v0; ps1[r] = v1;
    }
    if (l15 == 0) {
#pragma unroll
        for (int r = 0; r < 4; ++r) {
            sums[wv][lhi * 4 + r] = ps0[r];
            sums[wv][16 + lhi * 4 + r] = ps1[r];
        }
    }
    bar_lgkm();

    // ---- phase 2a: attn NT-stores FIRST, 4 rows per wave (start the stream) ----
#pragma unroll
    for (int rr = 0; rr < 4; ++rr) {
        int row = wv * 4 + rr;
        float tot = 0.f;
#pragma unroll
        for (int w = 0; w < 8; ++w) tot += sums[w][row];
        float inv = 1.f / tot;
        float* arow = attn_out + (((size_t)g * 2048 + n0 + row) << 10);
#pragma unroll
        for (int it = 0; it < 2; ++it) {
            int col = it * 512 + lane * 8;
            int byte = ((row << 11) + (col << 1)) ^ ((row & 7) << 4);
            s16x8 p = *(const s16x8*)(smem + byte);
            f32x4 w0 = {bf2f(p[0]) * inv, bf2f(p[1]) * inv, bf2f(p[2]) * inv, bf2f(p[3]) * inv};
            f32x4 w1 = {bf2f(p[4]) * inv, bf2f(p[5]) * inv, bf2f(p[6]) * inv, bf2f(p[7]) * inv};
            __builtin_nontemporal_store(w0, (f32x4*)(arow + col));
            __builtin_nontemporal_store(w1, (f32x4*)(arow + col + 4));
        }
    }

    // ---- phase 2b: PV partial over this wave's m-chunk, 2-deep V pipe ----
    f32x4 ctx0[4] = {}, ctx1[4] = {};
#pragma unroll
    for (int kk = 0; kk < 4; ++kk) {
        int col = wv * 128 + kk * 32 + lhi * 8;
        s16x8 pv[4];
#pragma unroll
        for (int ni = 0; ni < 4; ++ni) pv[ni] = vb[kk & 1][ni];
        if (kk < 2) {   // refill with kk+2
            int ncol = wv * 128 + (kk + 2) * 32 + lhi * 8;
#pragma unroll
            for (int ni = 0; ni < 4; ++ni)
                vb[kk][ni] = *(const s16x8*)&Vg[((ni * 16 + l15) << 10) + ncol];
        }
        int b0 = ((l15 << 11) + (col << 1)) ^ ((l15 & 7) << 4);
        int b1 = (((16 + l15) << 11) + (col << 1)) ^ ((l15 & 7) << 4);
        s16x8 pf0 = *(const s16x8*)(smem + b0);
        s16x8 pf1 = *(const s16x8*)(smem + b1);
#pragma unroll
        for (int ni = 0; ni < 4; ++ni) {
            ctx0[ni] = MFMA16(pf0, pv[ni], ctx0[ni]);
            ctx1[ni] = MFMA16(pf1, pv[ni], ctx1[ni]);
        }
    }

    // ---- phase 3: two-stage cross-wave ctx reduction (cx aliases Pl) ----
    bar_lgkm();                            // LDS reads retired; stores still flying
    float* cx = (float*)smem;              // [4][32][68]
    if (wv >= 4) {
        int q = wv - 4;
#pragma unroll
        for (int ni = 0; ni < 4; ++ni)
#pragma unroll
            for (int r = 0; r < 4; ++r) {
                cx[(q * 32 + lhi * 4 + r) * 68 + ni * 16 + l15] = ctx0[ni][r];
                cx[(q * 32 + 16 + lhi * 4 + r) * 68 + ni * 16 + l15] = ctx1[ni][r];
            }
    }
    bar_lgkm();
    if (wv < 4) {
#pragma unroll
        for (int ni = 0; ni < 4; ++ni)
#pragma unroll
            for (int r = 0; r < 4; ++r) {
                cx[(wv * 32 + lhi * 4 + r) * 68 + ni * 16 + l15] += ctx0[ni][r];
                cx[(wv * 32 + 16 + lhi * 4 + r) * 68 + ni * 16 + l15] += ctx1[ni][r];
            }
    }
    bar_lgkm();

    // ---- Wp projection: waves 0-1, 16 rows each ----
    if (wv < 2) {
        int rbase = wv * 16;
        float tot = 0.f;
#pragma unroll
        for (int w = 0; w < 8; ++w) tot += sums[w][rbase + l15];
        float invq = 1.f / tot;
        s16x8 ca[2];
#pragma unroll
        for (int kk = 0; kk < 2; ++kk)
#pragma unroll
            for (int j = 0; j < 8; ++j) {
                int k = kk * 32 + lhi * 8 + j;
                int ri = (rbase + l15) * 68 + k;
                float v = cx[ri] + cx[2176 + ri] + cx[4352 + ri] + cx[6528 + ri];
                ca[kk][j] = f2bf(v * invq);
            }
        f32x4 acc2[4] = {};
#pragma unroll
        for (int ni = 0; ni < 4; ++ni) {
            s16x8 b0 = *(const s16x8*)&WpT[((ni * 16 + l15) << 6) + lhi * 8];
            s16x8 b1 = *(const s16x8*)&WpT[((ni * 16 + l15) << 6) + 32 + lhi * 8];
            acc2[ni] = MFMA16(ca[0], b0, acc2[ni]);
            acc2[ni] = MFMA16(ca[1], b1, acc2[ni]);
        }
        const int hh = g >> 3, bb = g & 7;
#pragma unroll
        for (int ni = 0; ni < 4; ++ni)
#pragma unroll
            for (int r = 0; r < 4; ++r) {
                int n = n0 + rbase + lhi * 4 + r;
                int e2 = ni * 16 + l15;
                float ov = acc2[ni][r] + bp[e2];
                __builtin_nontemporal_store(
                    ov, ctx_out + ((size_t)bb * 2048 + n) * 512 + hh * 64 + e2);
            }
    }
}

// ---------------------------------------------------------------------------
extern "C" void kernel_launch(void* const* d_in, const int* in_sizes, int n_in,
                              void* d_out, int out_size, void* d_ws, size_t ws_size,
                              hipStream_t stream)
{
    const float* x     = (const float*)d_in[0];
    const float* xkv   = (const float*)d_in[1];
    const float* Wq    = (const float*)d_in[2];
    const float* bq    = (const float*)d_in[3];
    const float* Wsr   = (const float*)d_in[4];
    const float* bsr   = (const float*)d_in[5];
    const float* gamma = (const float*)d_in[6];
    const float* beta  = (const float*)d_in[7];
    const float* Wkv   = (const float*)d_in[8];
    const float* bkv   = (const float*)d_in[9];
    const float* Wp    = (const float*)d_in[10];
    const float* bp    = (const float*)d_in[11];

    float* ctx_out  = (float*)d_out;                       // 8*2048*512
    float* attn_out = ctx_out + (size_t)8 * 2048 * 512;    // 64*2048*1024

    // pre-attention scratch lives in the attn output region (rewritten later
    // only by attn_kernel, which reads exclusively from d_ws / d_in)
    char* sc = (char*)attn_out;
    float* xkf  = (float*)sc;  sc += (size_t)8192 * 512 * 4;
    short* WqT  = (short*)sc;  sc += (size_t)512 * 512 * 2;
    short* W2T  = (short*)sc;  sc += (size_t)512 * 1024 * 2;
    short* WkvT = (short*)sc;  sc += (size_t)1024 * 512 * 2;

    // attention inputs + LN stats in d_ws (~33.7 MB)
    char* ws = (char*)d_ws;
    short* Qb  = (short*)ws;   ws += (size_t)64 * 2048 * 64 * 2;
    short* Kb  = (short*)ws;   ws += (size_t)64 * 1024 * 64 * 2;
    short* VTb = (short*)ws;   ws += (size_t)64 * 64 * 1024 * 2;
    short* WpT = (short*)ws;   ws += (size_t)64 * 64 * 2;
    float* ssum = (float*)ws;  ws += (size_t)8192 * 4;
    float* ssq  = (float*)ws;  ws += (size_t)8192 * 4;

    hipMemsetAsync(ssum, 0, 2 * 8192 * sizeof(float), stream);   // ssum+ssq contiguous
    prep_all<<<400, 256, 0, stream>>>(Wq, Wsr, Wkv, Wp, WqT, W2T, WkvT, WpT);
    // fused: Q = x@Wq+bq -> Qb (scaled 0.125*log2e) | xk = conv1d(x_kv)+bsr -> xkf (+LN stats)
    gemm_qconv<<<768, 256, 0, stream>>>(x, xkv, WqT, W2T, bq, bsr, Qb, xkf, ssum, ssq);
    // kv = LN(xk) @ Wkv + bkv -> K[g][m][d], VT[g][dh][m]  (LN fused in A-staging)
    gemm_kv<<<512, 256, 0, stream>>>(xkf, WkvT, ssum, ssq, gamma, beta, bkv, Kb, VTb);
    attn_kernel<<<4096, 512, 0, stream>>>(Qb, Kb, VTb, WpT, bp, ctx_out, attn_out);
}

// Round 14
// 290.444 us; speedup vs baseline: 1.0352x; 1.0352x over previous
//
#include <hip/hip_runtime.h>
#include <cstdint>

using f32x4 = __attribute__((ext_vector_type(4))) float;
using s16x8 = __attribute__((ext_vector_type(8))) short;

__device__ __forceinline__ short f2bf(float f) {
    union { float f; uint32_t u; } x{f};
    uint32_t r = (x.u + 0x7fffu + ((x.u >> 16) & 1u)) >> 16;
    return (short)r;
}
__device__ __forceinline__ float bf2f(short s) {
    union { uint32_t u; float f; } x;
    x.u = ((uint32_t)(uint16_t)s) << 16;
    return x.f;
}

#define MFMA16(a, b, c) __builtin_amdgcn_mfma_f32_16x16x32_bf16(a, b, c, 0, 0, 0)

// barrier that does NOT drain vmcnt: global stores/loads stay in flight.
__device__ __forceinline__ void bar_lgkm() {
    asm volatile("s_waitcnt lgkmcnt(0)\n\ts_barrier" ::: "memory");
}

__device__ __forceinline__ void gl_lds16(const void* g, void* l) {
    __builtin_amdgcn_global_load_lds(
        (const __attribute__((address_space(1))) void*)(const void*)g,
        (__attribute__((address_space(3))) void*)l, 16, 0, 0);
}

// ---------------------------------------------------------------------------
// prep: blocks 0-191 = coalesced 64x64 LDS-transpose (Wq, Wkv);
//       blocks 192-399 = scalar W2T (row-permute, stride-2 reads) + WpT
// ---------------------------------------------------------------------------
__global__ __launch_bounds__(256) void prep_all(
    const float* __restrict__ Wq, const float* __restrict__ Wsr,
    const float* __restrict__ Wkv, const float* __restrict__ Wp,
    short* __restrict__ WqT, short* __restrict__ W2T,
    short* __restrict__ WkvT, short* __restrict__ WpT)
{
    const int b = blockIdx.x, tid = threadIdx.x;
    if (b < 192) {
        const float* src; short* dst; int K, N, tk, tn;
        if (b < 64) { src = Wq;  dst = WqT;  K = 512; N = 512;  tk = b >> 3; tn = b & 7; }
        else { int u = b - 64; src = Wkv; dst = WkvT; K = 512; N = 1024; tk = u >> 4; tn = u & 15; }
        const int k0 = tk * 64, n0 = tn * 64;
        __shared__ float t[64][65];
        const int lr = tid >> 2, lc = (tid & 3) * 16;
        const float* s = src + (size_t)(k0 + lr) * N + n0 + lc;
        float4 a0 = *(const float4*)s, a1 = *(const float4*)(s + 4);
        float4 a2 = *(const float4*)(s + 8), a3 = *(const float4*)(s + 12);
        *(float4*)&t[lr][lc]      = a0; *(float4*)&t[lr][lc + 4]  = a1;
        *(float4*)&t[lr][lc + 8]  = a2; *(float4*)&t[lr][lc + 12] = a3;
        __syncthreads();
        const int wn = tid >> 2, wk = (tid & 3) * 16;
        s16x8 o0, o1;
#pragma unroll
        for (int j = 0; j < 8; ++j) {
            o0[j] = f2bf(t[wk + j][wn]);
            o1[j] = f2bf(t[wk + 8 + j][wn]);
        }
        short* d = dst + (size_t)(n0 + wn) * K + k0 + wk;
        *(s16x8*)d = o0;
        *(s16x8*)(d + 8) = o1;
    } else {
        for (int u = (b - 192) * 256 + tid; u < 524288 + 4096; u += 208 * 256) {
            if (u < 524288) {
                int o = u >> 10, kk = u & 1023;
                int s2 = kk >> 9, i = kk & 511;
                W2T[u] = f2bf(Wsr[o * 1024 + i * 2 + s2]);     // W2T[o][s*512+i]
            } else {
                int v = u - 524288;
                int e = v >> 6, dh = v & 63;
                WpT[v] = f2bf(Wp[dh * 64 + e]);                // WpT[e][dh]
            }
        }
    }
}

__global__ __launch_bounds__(256) void ln_kernel(
    const float* __restrict__ xkf, const float* __restrict__ gamma,
    const float* __restrict__ beta, short* __restrict__ out)
{
    int row = blockIdx.x * 4 + (threadIdx.x >> 6);
    int lane = threadIdx.x & 63;
    const float* p = xkf + (size_t)row * 512 + lane * 8;
    float4 v0 = *(const float4*)p, v1 = *(const float4*)(p + 4);
    float vv[8] = {v0.x, v0.y, v0.z, v0.w, v1.x, v1.y, v1.z, v1.w};
    float s = 0.f, q = 0.f;
#pragma unroll
    for (int j = 0; j < 8; ++j) { s += vv[j]; q += vv[j] * vv[j]; }
#pragma unroll
    for (int m = 1; m < 64; m <<= 1) { s += __shfl_xor(s, m); q += __shfl_xor(q, m); }
    float mean = s * (1.f / 512.f);
    float var  = q * (1.f / 512.f) - mean * mean;
    float rstd = rsqrtf(var + 1e-5f);
    s16x8 o;
#pragma unroll
    for (int j = 0; j < 8; ++j)
        o[j] = f2bf((vv[j] - mean) * rstd * gamma[lane * 8 + j] + beta[lane * 8 + j]);
    *(s16x8*)(out + (size_t)row * 512 + lane * 8) = o;
}

// ---------------------------------------------------------------------------
// Fused Q-gemm (u 0-511) + conv-gemm (u 512-767), both AF32 staged.
// XCD-affinity swizzle: XCD x owns u in [x*96, x*96+96); the 4 n-tiles of an
// m-strip are consecutive u -> same XCD -> A-strip fetched once, L2-served.
// Q epilogue folds 0.125*log2(e) so attn can use exp2f.
// ---------------------------------------------------------------------------
__global__ __launch_bounds__(256) void gemm_qconv(
    const float* __restrict__ x, const float* __restrict__ xkv,
    const short* __restrict__ WqT, const short* __restrict__ W2T,
    const float* __restrict__ bq, const float* __restrict__ bsr,
    short* __restrict__ Qb, float* __restrict__ xkf)
{
    __shared__ short As[128 * 32];
    __shared__ short Bs[128 * 32];
    const int tid = threadIdx.x;
    const int wv = tid >> 6, lane = tid & 63;
    const int l15 = lane & 15, lhi = lane >> 4;
    const int wr = wv >> 1, wc = wv & 1;

    const int bid = blockIdx.x;
    const int u0 = (bid & 7) * 96 + (bid >> 3);          // 768 = 8 XCDs x 96
    const bool isQ = u0 < 512;
    const int u = isQ ? u0 : u0 - 512;
    const int m0 = (u >> 2) * 128, n0 = (u & 3) * 128;
    const int K = isQ ? 512 : 1024;
    const float* A = isQ ? x : xkv;
    const short* BT = isQ ? WqT : W2T;
    const float* bias = isQ ? bq : bsr;

    f32x4 acc[4][4] = {};

    const int nk = K >> 5;
    for (int kk = 0; kk < nk; ++kk) {
#pragma unroll
        for (int i = 0; i < 2; ++i) {
            int fo = wv * 2048 + i * 1024 + lane * 16;   // byte offset in 8KB tile
            int row = fo >> 6;
            int ks  = (fo & 63) >> 1;
            const float* src = A + (size_t)(m0 + row) * K + kk * 32 + ks;
            float4 a0 = *(const float4*)src;
            float4 a1 = *(const float4*)(src + 4);
            s16x8 pk;
            pk[0] = f2bf(a0.x); pk[1] = f2bf(a0.y); pk[2] = f2bf(a0.z); pk[3] = f2bf(a0.w);
            pk[4] = f2bf(a1.x); pk[5] = f2bf(a1.y); pk[6] = f2bf(a1.z); pk[7] = f2bf(a1.w);
            *(s16x8*)((char*)As + fo) = pk;
            gl_lds16(BT + (size_t)(n0 + row) * K + kk * 32 + ks, (char*)Bs + fo);
        }
        __syncthreads();
        s16x8 a[4], b[4];
#pragma unroll
        for (int mi = 0; mi < 4; ++mi)
            a[mi] = *(const s16x8*)&As[(wr * 64 + mi * 16 + l15) * 32 + lhi * 8];
#pragma unroll
        for (int ni = 0; ni < 4; ++ni)
            b[ni] = *(const s16x8*)&Bs[(wc * 64 + ni * 16 + l15) * 32 + lhi * 8];
#pragma unroll
        for (int mi = 0; mi < 4; ++mi)
#pragma unroll
            for (int ni = 0; ni < 4; ++ni)
                acc[mi][ni] = MFMA16(a[mi], b[ni], acc[mi][ni]);
        __syncthreads();
    }

#pragma unroll
    for (int mi = 0; mi < 4; ++mi) {
#pragma unroll
        for (int ni = 0; ni < 4; ++ni) {
#pragma unroll
            for (int r = 0; r < 4; ++r) {
                int grow = m0 + wr * 64 + mi * 16 + lhi * 4 + r;
                int gcol = n0 + wc * 64 + ni * 16 + l15;
                float v = acc[mi][ni][r] + bias[gcol];
                if (isQ) {
                    // Qb[g=h*8+b][n][dh], scale 0.125*log2(e) for exp2 softmax
                    int h = gcol >> 6, dh = gcol & 63;
                    int bb = grow >> 11, n = grow & 2047;
                    Qb[(((size_t)(h * 8 + bb) * 2048 + n) << 6) + dh] = f2bf(v * 0.18033688f);
                } else {
                    xkf[(size_t)grow * 512 + gcol] = v;
                }
            }
        }
    }
}

// ---------------------------------------------------------------------------
// KV gemm: A bf16 via global_load_lds, KV scatter epilogue (permute-bug layout)
// XCD-affinity: XCD x owns u in [x*64, x*64+64); 8 n-tiles of an m-strip are
// consecutive u -> same XCD.
// ---------------------------------------------------------------------------
__global__ __launch_bounds__(256) void gemm_kv(
    const short* __restrict__ A, const short* __restrict__ BT,
    const float* __restrict__ bias,
    short* __restrict__ Kb, short* __restrict__ VTb)
{
    __shared__ short As[128 * 32];
    __shared__ short Bs[128 * 32];
    const int tid = threadIdx.x;
    const int wv = tid >> 6, lane = tid & 63;
    const int l15 = lane & 15, lhi = lane >> 4;
    const int wr = wv >> 1, wc = wv & 1;
    const int K = 512;
    const int u = (blockIdx.x & 7) * 64 + (blockIdx.x >> 3);   // 512 = 8 x 64
    const int m0 = (u >> 3) * 128, n0 = (u & 7) * 128;

    f32x4 acc[4][4] = {};

    const int nk = K >> 5;
    for (int kk = 0; kk < nk; ++kk) {
#pragma unroll
        for (int i = 0; i < 2; ++i) {
            int fo = wv * 2048 + i * 1024 + lane * 16;
            int row = fo >> 6;
            int ks  = (fo & 63) >> 1;
            gl_lds16(A + (size_t)(m0 + row) * K + kk * 32 + ks, (char*)As + fo);
            gl_lds16(BT + (size_t)(n0 + row) * K + kk * 32 + ks, (char*)Bs + fo);
        }
        __syncthreads();
        s16x8 a[4], b[4];
#pragma unroll
        for (int mi = 0; mi < 4; ++mi)
            a[mi] = *(const s16x8*)&As[(wr * 64 + mi * 16 + l15) * 32 + lhi * 8];
#pragma unroll
        for (int ni = 0; ni < 4; ++ni)
            b[ni] = *(const s16x8*)&Bs[(wc * 64 + ni * 16 + l15) * 32 + lhi * 8];
#pragma unroll
        for (int mi = 0; mi < 4; ++mi)
#pragma unroll
            for (int ni = 0; ni < 4; ++ni)
                acc[mi][ni] = MFMA16(a[mi], b[ni], acc[mi][ni]);
        __syncthreads();
    }

#pragma unroll
    for (int mi = 0; mi < 4; ++mi) {
#pragma unroll
        for (int ni = 0; ni < 4; ++ni) {
#pragma unroll
            for (int r = 0; r < 4; ++r) {
                int grow = m0 + wr * 64 + mi * 16 + lhi * 4 + r;
                int gcol = n0 + wc * 64 + ni * 16 + l15;
                float v = acc[mi][ni][r] + bias[gcol];
                int kvsel = gcol >> 9, h = (gcol >> 6) & 7, dh = gcol & 63;
                int bb = grow >> 10, t = grow & 1023;
                int g2 = t >> 4, m = ((t & 15) << 6) + bb * 8 + h;
                if (kvsel == 0)
                    Kb[(((size_t)g2 * 1024 + m) << 6) + dh] = f2bf(v);        // K[g][m][d]
                else
                    VTb[(((size_t)g2 * 64 + dh) << 10) + m] = f2bf(v);        // VT[g][dh][m]
            }
        }
    }
}

// ---------------------------------------------------------------------------
// attention: 8 waves (512 thr), 32 q-rows/block, m=1024 split 8 ways.
// lgkm-only barriers; NT attn stores issued FIRST after the phase-1 barrier
// (write stream starts earliest; V prefetched pre-barrier so PV unaffected).
// exp2f softmax (log2e folded into Q). NT ctx stores (write-once).
// __launch_bounds__(512,4): compiler picks regs freely, NO spills (r11 lesson:
// (512,8) forced 32 VGPR -> 0.9 GB scratch spill traffic, 420 us).
// ---------------------------------------------------------------------------
__global__ __launch_bounds__(512, 4) void attn_kernel(
    const short* __restrict__ Qb, const short* __restrict__ Kb,
    const short* __restrict__ VTb, const short* __restrict__ WpT,
    const float* __restrict__ bp,
    float* __restrict__ ctx_out, float* __restrict__ attn_out)
{
    __shared__ __align__(16) char smem[65536];   // Pl: 32x1024 bf16 | cx: [4][32][68] f32 (aliased)
    __shared__ float sums[8][32];

    // XCD-aware swizzle (4096 blocks, 8 XCDs)
    const int bid = blockIdx.x;
    const int swz = ((bid & 7) << 9) | (bid >> 3);
    const int g  = swz >> 6;
    const int n0 = (swz & 63) << 5;
    const int tid = threadIdx.x;
    const int wv = tid >> 6, lane = tid & 63;
    const int l15 = lane & 15, lhi = lane >> 4;

    // Q a-frags for both row-groups (scale 0.125*log2e folded at Q-gemm)
    s16x8 qa00, qa01, qa10, qa11;
    {
        size_t qb0 = (((size_t)g * 2048 + n0 + l15) << 6) + lhi * 8;
        size_t qb1 = (((size_t)g * 2048 + n0 + 16 + l15) << 6) + lhi * 8;
        qa00 = *(const s16x8*)&Qb[qb0];
        qa01 = *(const s16x8*)&Qb[qb0 + 32];
        qa10 = *(const s16x8*)&Qb[qb1];
        qa11 = *(const s16x8*)&Qb[qb1 + 32];
    }

    // ---- phase 1: QK^T over this wave's m-chunk (128) x 32 rows, 4-deep K pipe ----
    const short* Kg = Kb + ((size_t)g << 16);
    s16x8 kf[4][2];
#pragma unroll
    for (int p = 0; p < 4; ++p) {
        const short* kr = Kg + (((wv * 8 + p) * 16 + l15) << 6) + lhi * 8;
        kf[p][0] = *(const s16x8*)kr;
        kf[p][1] = *(const s16x8*)(kr + 32);
    }
    float ps0[4] = {}, ps1[4] = {};
#pragma unroll
    for (int i = 0; i < 8; ++i) {
        s16x8 k0 = kf[i & 3][0], k1 = kf[i & 3][1];
        if (i < 4) {   // refill slot with iter i+4 (static index, full unroll)
            const short* kr = Kg + (((wv * 8 + i + 4) * 16 + l15) << 6) + lhi * 8;
            kf[i][0] = *(const s16x8*)kr;
            kf[i][1] = *(const s16x8*)(kr + 32);
        }
        int mf = wv * 8 + i;
        f32x4 s0 = {0.f, 0.f, 0.f, 0.f};
        s0 = MFMA16(qa00, k0, s0);
        s0 = MFMA16(qa01, k1, s0);
        f32x4 s1 = {0.f, 0.f, 0.f, 0.f};
        s1 = MFMA16(qa10, k0, s1);
        s1 = MFMA16(qa11, k1, s1);
#pragma unroll
        for (int r = 0; r < 4; ++r) {
            float e0 = exp2f(s0[r]);
            ps0[r] += e0;
            int row0 = lhi * 4 + r;
            int byte0 = ((row0 << 11) + ((mf * 16 + l15) << 1)) ^ ((row0 & 7) << 4);
            *(short*)(smem + byte0) = f2bf(e0);
            float e1 = exp2f(s1[r]);
            ps1[r] += e1;
            int row1 = 16 + lhi * 4 + r;
            int byte1 = ((row1 << 11) + ((mf * 16 + l15) << 1)) ^ ((row1 & 7) << 4);
            *(short*)(smem + byte1) = f2bf(e1);
        }
    }

    // V prologue: issue before the barrier (vmcnt not drained by bar_lgkm)
    const short* Vg = VTb + ((size_t)g << 16);
    s16x8 vb[2][4];
#pragma unroll
    for (int ni = 0; ni < 4; ++ni) {
        vb[0][ni] = *(const s16x8*)&Vg[((ni * 16 + l15) << 10) + wv * 128 + lhi * 8];
        vb[1][ni] = *(const s16x8*)&Vg[((ni * 16 + l15) << 10) + wv * 128 + 32 + lhi * 8];
    }

#pragma unroll
    for (int r = 0; r < 4; ++r) {
        float v0 = ps0[r], v1 = ps1[r];
        v0 += __shfl_xor(v0, 1); v1 += __shfl_xor(v1, 1);
        v0 += __shfl_xor(v0, 2); v1 += __shfl_xor(v1, 2);
        v0 += __shfl_xor(v0, 4); v1 += __shfl_xor(v1, 4);
        v0 += __shfl_xor(v0, 8); v1 += __shfl_xor(v1, 8);
        ps0[r] = v0; ps1[r] = v1;
    }
    if (l15 == 0) {
#pragma unroll
        for (int r = 0; r < 4; ++r) {
            sums[wv][lhi * 4 + r] = ps0[r];
            sums[wv][16 + lhi * 4 + r] = ps1[r];
        }
    }
    bar_lgkm();

    // ---- phase 2a: attn NT-stores FIRST, 4 rows per wave (start the stream) ----
#pragma unroll
    for (int rr = 0; rr < 4; ++rr) {
        int row = wv * 4 + rr;
        float tot = 0.f;
#pragma unroll
        for (int w = 0; w < 8; ++w) tot += sums[w][row];
        float inv = 1.f / tot;
        float* arow = attn_out + (((size_t)g * 2048 + n0 + row) << 10);
#pragma unroll
        for (int it = 0; it < 2; ++it) {
            int col = it * 512 + lane * 8;
            int byte = ((row << 11) + (col << 1)) ^ ((row & 7) << 4);
            s16x8 p = *(const s16x8*)(smem + byte);
            f32x4 w0 = {bf2f(p[0]) * inv, bf2f(p[1]) * inv, bf2f(p[2]) * inv, bf2f(p[3]) * inv};
            f32x4 w1 = {bf2f(p[4]) * inv, bf2f(p[5]) * inv, bf2f(p[6]) * inv, bf2f(p[7]) * inv};
            __builtin_nontemporal_store(w0, (f32x4*)(arow + col));
            __builtin_nontemporal_store(w1, (f32x4*)(arow + col + 4));
        }
    }

    // ---- phase 2b: PV partial over this wave's m-chunk, 2-deep V pipe ----
    f32x4 ctx0[4] = {}, ctx1[4] = {};
#pragma unroll
    for (int kk = 0; kk < 4; ++kk) {
        int col = wv * 128 + kk * 32 + lhi * 8;
        s16x8 pv[4];
#pragma unroll
        for (int ni = 0; ni < 4; ++ni) pv[ni] = vb[kk & 1][ni];
        if (kk < 2) {   // refill with kk+2
            int ncol = wv * 128 + (kk + 2) * 32 + lhi * 8;
#pragma unroll
            for (int ni = 0; ni < 4; ++ni)
                vb[kk][ni] = *(const s16x8*)&Vg[((ni * 16 + l15) << 10) + ncol];
        }
        int b0 = ((l15 << 11) + (col << 1)) ^ ((l15 & 7) << 4);
        int b1 = (((16 + l15) << 11) + (col << 1)) ^ ((l15 & 7) << 4);
        s16x8 pf0 = *(const s16x8*)(smem + b0);
        s16x8 pf1 = *(const s16x8*)(smem + b1);
#pragma unroll
        for (int ni = 0; ni < 4; ++ni) {
            ctx0[ni] = MFMA16(pf0, pv[ni], ctx0[ni]);
            ctx1[ni] = MFMA16(pf1, pv[ni], ctx1[ni]);
        }
    }

    // ---- phase 3: two-stage cross-wave ctx reduction (cx aliases Pl) ----
    bar_lgkm();                            // LDS reads retired; stores still flying
    float* cx = (float*)smem;              // [4][32][68]
    if (wv >= 4) {
        int q = wv - 4;
#pragma unroll
        for (int ni = 0; ni < 4; ++ni)
#pragma unroll
            for (int r = 0; r < 4; ++r) {
                cx[(q * 32 + lhi * 4 + r) * 68 + ni * 16 + l15] = ctx0[ni][r];
                cx[(q * 32 + 16 + lhi * 4 + r) * 68 + ni * 16 + l15] = ctx1[ni][r];
            }
    }
    bar_lgkm();
    if (wv < 4) {
#pragma unroll
        for (int ni = 0; ni < 4; ++ni)
#pragma unroll
            for (int r = 0; r < 4; ++r) {
                cx[(wv * 32 + lhi * 4 + r) * 68 + ni * 16 + l15] += ctx0[ni][r];
                cx[(wv * 32 + 16 + lhi * 4 + r) * 68 + ni * 16 + l15] += ctx1[ni][r];
            }
    }
    bar_lgkm();

    // ---- Wp projection: waves 0-1, 16 rows each ----
    if (wv < 2) {
        int rbase = wv * 16;
        float tot = 0.f;
#pragma unroll
        for (int w = 0; w < 8; ++w) tot += sums[w][rbase + l15];
        float invq = 1.f / tot;
        s16x8 ca[2];
#pragma unroll
        for (int kk = 0; kk < 2; ++kk)
#pragma unroll
            for (int j = 0; j < 8; ++j) {
                int k = kk * 32 + lhi * 8 + j;
                int ri = (rbase + l15) * 68 + k;
                float v = cx[ri] + cx[2176 + ri] + cx[4352 + ri] + cx[6528 + ri];
                ca[kk][j] = f2bf(v * invq);
            }
        f32x4 acc2[4] = {};
#pragma unroll
        for (int ni = 0; ni < 4; ++ni) {
            s16x8 b0 = *(const s16x8*)&WpT[((ni * 16 + l15) << 6) + lhi * 8];
            s16x8 b1 = *(const s16x8*)&WpT[((ni * 16 + l15) << 6) + 32 + lhi * 8];
            acc2[ni] = MFMA16(ca[0], b0, acc2[ni]);
            acc2[ni] = MFMA16(ca[1], b1, acc2[ni]);
        }
        const int hh = g >> 3, bb = g & 7;
#pragma unroll
        for (int ni = 0; ni < 4; ++ni)
#pragma unroll
            for (int r = 0; r < 4; ++r) {
                int n = n0 + rbase + lhi * 4 + r;
                int e2 = ni * 16 + l15;
                float ov = acc2[ni][r] + bp[e2];
                __builtin_nontemporal_store(
                    ov, ctx_out + ((size_t)bb * 2048 + n) * 512 + hh * 64 + e2);
            }
    }
}

// ---------------------------------------------------------------------------
extern "C" void kernel_launch(void* const* d_in, const int* in_sizes, int n_in,
                              void* d_out, int out_size, void* d_ws, size_t ws_size,
                              hipStream_t stream)
{
    const float* x     = (const float*)d_in[0];
    const float* xkv   = (const float*)d_in[1];
    const float* Wq    = (const float*)d_in[2];
    const float* bq    = (const float*)d_in[3];
    const float* Wsr   = (const float*)d_in[4];
    const float* bsr   = (const float*)d_in[5];
    const float* gamma = (const float*)d_in[6];
    const float* beta  = (const float*)d_in[7];
    const float* Wkv   = (const float*)d_in[8];
    const float* bkv   = (const float*)d_in[9];
    const float* Wp    = (const float*)d_in[10];
    const float* bp    = (const float*)d_in[11];

    float* ctx_out  = (float*)d_out;                       // 8*2048*512
    float* attn_out = ctx_out + (size_t)8 * 2048 * 512;    // 64*2048*1024

    // pre-attention scratch lives in the attn output region (rewritten later
    // only by attn_kernel, which reads exclusively from d_ws / d_in)
    char* sc = (char*)attn_out;
    float* xkf  = (float*)sc;  sc += (size_t)8192 * 512 * 4;
    short* xkln = (short*)sc;  sc += (size_t)8192 * 512 * 2;
    short* WqT  = (short*)sc;  sc += (size_t)512 * 512 * 2;
    short* W2T  = (short*)sc;  sc += (size_t)512 * 1024 * 2;
    short* WkvT = (short*)sc;  sc += (size_t)1024 * 512 * 2;

    // attention inputs in d_ws (~33.6 MB)
    char* ws = (char*)d_ws;
    short* Qb  = (short*)ws;   ws += (size_t)64 * 2048 * 64 * 2;
    short* Kb  = (short*)ws;   ws += (size_t)64 * 1024 * 64 * 2;
    short* VTb = (short*)ws;   ws += (size_t)64 * 64 * 1024 * 2;
    short* WpT = (short*)ws;   ws += (size_t)64 * 64 * 2;

    prep_all<<<400, 256, 0, stream>>>(Wq, Wsr, Wkv, Wp, WqT, W2T, WkvT, WpT);
    // fused: Q = x@Wq+bq -> Qb (scaled 0.125*log2e) | xk = conv1d(x_kv)+bsr -> xkf
    gemm_qconv<<<768, 256, 0, stream>>>(x, xkv, WqT, W2T, bq, bsr, Qb, xkf);
    ln_kernel<<<2048, 256, 0, stream>>>(xkf, gamma, beta, xkln);
    // kv = LN(xk) @ Wkv + bkv -> K[g][m][d], VT[g][dh][m]
    gemm_kv<<<512, 256, 0, stream>>>(xkln, WkvT, bkv, Kb, VTb);
    attn_kernel<<<4096, 512, 0, stream>>>(Qb, Kb, VTb, WpT, bp, ctx_out, attn_out);
}